// Round 5
// baseline (370.748 us; speedup 1.0000x reference)
//
#include <hip/hip_runtime.h>
#include <hip/hip_bf16.h>
#include <cstdint>
#include <cstddef>

// ---------- types / helpers ----------
typedef __attribute__((ext_vector_type(8)))  short bf16x8;
typedef __attribute__((ext_vector_type(4)))  float f32x4;
typedef __attribute__((ext_vector_type(16))) float f32x16;
typedef __attribute__((ext_vector_type(4)))  int   i32x4;

#define DEVINL __device__ __forceinline__

#define ATT_SCALE 0.07905694150420949f                    // 1/sqrt(160)
#define QSCALE    (0.07905694150420949f * 1.4426950408889634f)  // fold log2(e): softmax in exp2 domain

DEVINL unsigned short f2bf(float f) {
  unsigned int u = __float_as_uint(f);
  u += 0x7fff + ((u >> 16) & 1);   // round-to-nearest-even
  return (unsigned short)(u >> 16);
}

DEVINL int cvtpk(float lo, float hi) {   // word = (bf16(lo), bf16(hi))
  int r;
  asm("v_cvt_pk_bf16_f32 %0, %1, %2" : "=v"(r) : "v"(lo), "v"(hi));
  return r;
}

// global -> LDS staging: 16B per lane. lds_u must be wave-uniform; HW adds lane*16.
DEVINL void stage16(const unsigned short* __restrict__ g, unsigned short* lds_u, int lane) {
  (void)lane;
  __builtin_amdgcn_global_load_lds((const __attribute__((address_space(1))) void*)g,
                                   (__attribute__((address_space(3))) void*)lds_u, 16, 0, 0);
}

// ---------- elementwise conversions ----------
__global__ void k_cvt_x(const float* __restrict__ x, unsigned short* __restrict__ o, int n) {
  int i = (blockIdx.x * blockDim.x + threadIdx.x) * 4;
  if (i >= n) return;
  float4 v = *reinterpret_cast<const float4*>(x + i);
  ushort4 r;
  r.x = f2bf(v.x); r.y = f2bf(v.y); r.z = f2bf(v.z); r.w = f2bf(v.w);
  *reinterpret_cast<ushort4*>(o + i) = r;
}

// All 7 weight transposes in one launch. W[K][N] fp32 -> WT[N][K] bf16.
struct TwArgs { const float* W[7]; unsigned short* D[7]; };
__global__ void k_tw_all(TwArgs a) {
  __shared__ float t[32][33];
  const int bid = blockIdx.x;
  int w, K, N, bx, by;
  if (bid < 3072)      { w = bid >> 10; int r = bid & 1023; K = 2048; N = 512;  bx = r & 15; by = r >> 4; }
  else if (bid < 6144) { int r = bid - 3072; w = 3 + (r >> 10); r &= 1023; K = 512; N = 2048; bx = r & 63; by = r >> 6; }
  else                 { int r = bid - 6144; w = 6; K = 512; N = 512; bx = r & 15; by = r >> 4; }
  const float* W = a.W[w];
  unsigned short* D = a.D[w];
  const int n0 = bx * 32, k0 = by * 32;
  const int tx = threadIdx.x, ty = threadIdx.y;  // (32,8)
#pragma unroll
  for (int j = 0; j < 4; j++)
    t[ty + j * 8][tx] = W[(size_t)(k0 + ty + j * 8) * N + n0 + tx];
  __syncthreads();
#pragma unroll
  for (int j = 0; j < 4; j++)
    D[(size_t)(n0 + ty + j * 8) * K + k0 + tx] = f2bf(t[tx][ty + j * 8]);
}

// ---------- fragment-linear K/V scatter offsets (32x32x16 MFMA operand layout) ----------
// K per (b,h,it): 20 frags (kvt*10+ks) of 512 shorts; lane l gets K[kv=kvt*32+(l&31)][d=ks*16+(l>>5)*8+e]
DEVINL size_t koff(int bh, int t, int d) {
  const int it = t >> 6, t6 = t & 63;
  const int kvt = t6 >> 5, lanelo = t6 & 31;
  const int ks = d >> 4, hi = (d >> 3) & 1, e = d & 7;
  return ((size_t)bh * 32 + it) * 10240 + (size_t)(kvt * 10 + ks) * 512 + (hi * 32 + lanelo) * 8 + e;
}
// V per (b,h,it): 16 frags (dvt*4+ks) of 512 shorts; lane l gets V[kv=ks*16+(l>>5)*8+e][dv=dvt*32+(l&31)]
DEVINL size_t voff(int bh, int t, int dv) {
  const int it = t >> 6, t6 = t & 63;
  const int ks = t6 >> 4, hi = (t6 >> 3) & 1, e = t6 & 7;
  const int dvt = dv >> 5, lanelo = dv & 31;
  return ((size_t)bh * 32 + it) * 8192 + (size_t)(dvt * 4 + ks) * 512 + (hi * 32 + lanelo) * 8 + e;
}

// ---------- GEMM stage 1: C[M][1536] = x[M][2048] * WTcat1 + bias -> [ckv | cq | krp] ----------
__global__ __launch_bounds__(256) void k_gemm1(const unsigned short* __restrict__ A,
                                               const unsigned short* __restrict__ BT,
                                               const float* __restrict__ bias0,
                                               const float* __restrict__ bias1,
                                               const float* __restrict__ bias2,
                                               unsigned short* __restrict__ o0,
                                               unsigned short* __restrict__ o1,
                                               float* __restrict__ o2) {
  __shared__ unsigned short sA[128 * 64];
  __shared__ unsigned short sB[128 * 64];
  const int K = 2048;
  const int tid = threadIdx.x;
  const int lane = tid & 63, wid = tid >> 6;
  const int wr = wid >> 1, wc = wid & 1;
  const int row0 = blockIdx.y * 128, col0 = blockIdx.x * 128;
  const int lc = lane & 15, lg = lane >> 4;
  const int srow = lane >> 3, scol = (lane & 7) * 8;

  f32x4 acc[4][4];
#pragma unroll
  for (int m = 0; m < 4; m++)
#pragma unroll
    for (int n = 0; n < 4; n++) acc[m][n] = f32x4{0.f, 0.f, 0.f, 0.f};

  for (int k0 = 0; k0 < K; k0 += 64) {
#pragma unroll
    for (int i = 0; i < 4; i++) {
      const int chunk = wid * 4 + i;
      const int r = chunk * 8 + srow;
      stage16(A + (size_t)(row0 + r) * K + k0 + scol, sA + chunk * 512, lane);
      stage16(BT + (size_t)(col0 + r) * K + k0 + scol, sB + chunk * 512, lane);
    }
    asm volatile("s_waitcnt vmcnt(0)" ::: "memory");
    __syncthreads();
#pragma unroll
    for (int ks = 0; ks < 2; ks++) {
      bf16x8 af[4], bfr[4];
#pragma unroll
      for (int m = 0; m < 4; m++)
        af[m] = *reinterpret_cast<const bf16x8*>(sA + (wr * 64 + m * 16 + lc) * 64 + ks * 32 + lg * 8);
#pragma unroll
      for (int n = 0; n < 4; n++)
        bfr[n] = *reinterpret_cast<const bf16x8*>(sB + (wc * 64 + n * 16 + lc) * 64 + ks * 32 + lg * 8);
#pragma unroll
      for (int m = 0; m < 4; m++)
#pragma unroll
        for (int n = 0; n < 4; n++)
          acc[m][n] = __builtin_amdgcn_mfma_f32_16x16x32_bf16(af[m], bfr[n], acc[m][n], 0, 0, 0);
    }
    __syncthreads();
  }

  const int lr = lg * 4;
#pragma unroll
  for (int m = 0; m < 4; m++)
#pragma unroll
    for (int n = 0; n < 4; n++) {
      const int col = col0 + wc * 64 + n * 16 + lc;
      const float bv = (col < 512) ? bias0[col] : (col < 1024) ? bias1[col - 512] : bias2[col - 1024];
#pragma unroll
      for (int r = 0; r < 4; r++) {
        const int row = row0 + wr * 64 + m * 16 + lr + r;
        const float v = acc[m][n][r] + bv;
        if (col < 512)        o0[(size_t)row * 512 + col] = f2bf(v);
        else if (col < 1024)  o1[(size_t)row * 512 + col - 512] = f2bf(v);
        else                  o2[(size_t)row * 512 + col - 1024] = v;
      }
    }
}

// ---------- GEMM stage 2 (merged): bx<32 -> ckv@[UK|UV] (K/V frag); bx>=32 -> cq@[UQ|QR] ----------
__global__ __launch_bounds__(256) void k_gemm2(const unsigned short* __restrict__ ckv,
                                               const unsigned short* __restrict__ cq,
                                               const unsigned short* __restrict__ WT2,
                                               const unsigned short* __restrict__ WT3,
                                               const float* __restrict__ bUK,
                                               const float* __restrict__ bUV,
                                               const float* __restrict__ bUQ,
                                               const float* __restrict__ bQR,
                                               unsigned short* __restrict__ Kfb,
                                               unsigned short* __restrict__ Vfb,
                                               unsigned short* __restrict__ Qbuf,
                                               float* __restrict__ qrp) {
  __shared__ unsigned short sA[128 * 64];
  __shared__ unsigned short sB[128 * 64];
  const int K = 512;
  const bool m11 = blockIdx.x < 32;
  const unsigned short* A  = m11 ? ckv : cq;
  const unsigned short* BT = m11 ? WT2 : WT3;
  const int tid = threadIdx.x;
  const int lane = tid & 63, wid = tid >> 6;
  const int wr = wid >> 1, wc = wid & 1;
  const int row0 = blockIdx.y * 128;
  const int col0 = (m11 ? blockIdx.x : (blockIdx.x - 32)) * 128;
  const int lc = lane & 15, lg = lane >> 4;
  const int srow = lane >> 3, scol = (lane & 7) * 8;

  f32x4 acc[4][4];
#pragma unroll
  for (int m = 0; m < 4; m++)
#pragma unroll
    for (int n = 0; n < 4; n++) acc[m][n] = f32x4{0.f, 0.f, 0.f, 0.f};

  for (int k0 = 0; k0 < K; k0 += 64) {
#pragma unroll
    for (int i = 0; i < 4; i++) {
      const int chunk = wid * 4 + i;
      const int r = chunk * 8 + srow;
      stage16(A + (size_t)(row0 + r) * K + k0 + scol, sA + chunk * 512, lane);
      stage16(BT + (size_t)(col0 + r) * K + k0 + scol, sB + chunk * 512, lane);
    }
    asm volatile("s_waitcnt vmcnt(0)" ::: "memory");
    __syncthreads();
#pragma unroll
    for (int ks = 0; ks < 2; ks++) {
      bf16x8 af[4], bfr[4];
#pragma unroll
      for (int m = 0; m < 4; m++)
        af[m] = *reinterpret_cast<const bf16x8*>(sA + (wr * 64 + m * 16 + lc) * 64 + ks * 32 + lg * 8);
#pragma unroll
      for (int n = 0; n < 4; n++)
        bfr[n] = *reinterpret_cast<const bf16x8*>(sB + (wc * 64 + n * 16 + lc) * 64 + ks * 32 + lg * 8);
#pragma unroll
      for (int m = 0; m < 4; m++)
#pragma unroll
        for (int n = 0; n < 4; n++)
          acc[m][n] = __builtin_amdgcn_mfma_f32_16x16x32_bf16(af[m], bfr[n], acc[m][n], 0, 0, 0);
    }
    __syncthreads();
  }

  const int lr = lg * 4;
#pragma unroll
  for (int m = 0; m < 4; m++)
#pragma unroll
    for (int n = 0; n < 4; n++) {
      const int col = col0 + wc * 64 + n * 16 + lc;
      float bv;
      if (m11) bv = (col < 2048) ? bUK[col] : bUV[col - 2048];
      else     bv = (col < 2048) ? bUQ[col] : bQR[col - 2048];
#pragma unroll
      for (int r = 0; r < 4; r++) {
        const int row = row0 + wr * 64 + m * 16 + lr + r;
        const float v = acc[m][n][r] + bv;
        const int b = row >> 11, t = row & 2047;
        if (m11) {
          if (col < 2048) {
            const int h = col >> 7, d = col & 127;
            Kfb[koff(b * 16 + h, t, d)] = f2bf(v);
          } else {
            const int c = col - 2048, h = c >> 7, dv = c & 127;
            Vfb[voff(b * 16 + h, t, dv)] = f2bf(v);
          }
        } else {
          if (col < 2048) {
            const int h = col >> 7, d = col & 127;
            Qbuf[((size_t)(b * 16 + h) * 2048 + t) * 160 + d] = f2bf(v * QSCALE);
          } else {
            qrp[(size_t)row * 512 + col - 2048] = v;
          }
        }
      }
    }
}

// ---------- RoPE: pre[row][512] fp32 -> Q(row-major, QSCALE) / K(frag layout) ----------
__global__ void k_rope(const float* __restrict__ qpre, const float* __restrict__ kpre,
                       unsigned short* __restrict__ Qb, unsigned short* __restrict__ Kf) {
  const int idx = blockIdx.x * blockDim.x + threadIdx.x;  // 0 .. 2*1048576-1
  const int which = idx >> 20;
  const int e = idx & 1048575;
  const int i = e & 15, h = (e >> 4) & 15, row = e >> 8;
  const int t = row & 2047, b = row >> 11;
  const float* pre = which ? kpre : qpre;
  const float x1 = pre[(size_t)row * 512 + h * 32 + 2 * i];
  const float x2 = pre[(size_t)row * 512 + h * 32 + 2 * i + 1];
  const float f = exp2f(-(float)i * (13.287712379549449f / 16.f));  // 10000^(-i/16)
  const float th = (float)t * f;
  float sv, cv;
  sincosf(th, &sv, &cv);
  const float o1 = x1 * cv - x2 * sv, o2 = x1 * sv + x2 * cv;
  if (which == 0) {
    const size_t base = ((size_t)(b * 16 + h) * 2048 + t) * 160 + 128;
    Qb[base + i]      = f2bf(o1 * QSCALE);
    Qb[base + 16 + i] = f2bf(o2 * QSCALE);
  } else {
    Kf[koff(b * 16 + h, t, 128 + i)] = f2bf(o1);
    Kf[koff(b * 16 + h, t, 144 + i)] = f2bf(o2);
  }
}

// ---------- attention helpers ----------
DEVINL float vmax32(const f32x16& a, const f32x16& b) {  // tree reduction, depth ~5
  float t[16];
#pragma unroll
  for (int j = 0; j < 16; j++) t[j] = fmaxf(a[j], b[j]);
#pragma unroll
  for (int s = 8; s >= 1; s >>= 1)
#pragma unroll
    for (int j = 0; j < s; j++) t[j] = fmaxf(t[j], t[j + s]);
  return t[0];
}

DEVINL void loadV(const unsigned short* __restrict__ Vt, bf16x8 v[16], int lane) {
#pragma unroll
  for (int f = 0; f < 16; f++)
    v[f] = *reinterpret_cast<const bf16x8*>(Vt + (size_t)f * 512 + lane * 8);
}

// one 64-key sub-iteration: QK (LDS) -> online softmax -> in-reg P pack -> PV
DEVINL void subiter(const unsigned short* __restrict__ sKb, const bf16x8 qf[10],
                    const bf16x8 vfr[16], f32x16 o[4], float& mrun, float& lrun,
                    int lane, int hi) {
  f32x16 s0 = {}, s1 = {};
  __builtin_amdgcn_s_setprio(1);
#pragma unroll
  for (int ks = 0; ks < 10; ks++) {
    bf16x8 kf0 = *reinterpret_cast<const bf16x8*>(sKb + (size_t)ks * 512 + lane * 8);
    s0 = __builtin_amdgcn_mfma_f32_32x32x16_bf16(kf0, qf[ks], s0, 0, 0, 0);
    bf16x8 kf1 = *reinterpret_cast<const bf16x8*>(sKb + (size_t)(10 + ks) * 512 + lane * 8);
    s1 = __builtin_amdgcn_mfma_f32_32x32x16_bf16(kf1, qf[ks], s1, 0, 0, 0);
  }
  __builtin_amdgcn_s_setprio(0);

  float mx = vmax32(s0, s1);
  mx = fmaxf(mx, __shfl_xor(mx, 32));

  if (__any(mx > mrun + 8.f)) {            // defer-max: rescale only on real growth
    const float mn = fmaxf(mrun, mx);
    const float corr = exp2f(mrun - mn);
    lrun *= corr;
#pragma unroll
    for (int d = 0; d < 4; d++)
#pragma unroll
      for (int r = 0; r < 16; r++) o[d][r] *= corr;
    mrun = mn;
  }

  float pe0[16], pe1[16];
#pragma unroll
  for (int r = 0; r < 16; r++) pe0[r] = exp2f(s0[r] - mrun);
#pragma unroll
  for (int r = 0; r < 16; r++) pe1[r] = exp2f(s1[r] - mrun);
  // tree sum of 32
  float a[16];
#pragma unroll
  for (int j = 0; j < 8; j++) {
    a[j]     = pe0[2 * j] + pe0[2 * j + 1];
    a[8 + j] = pe1[2 * j] + pe1[2 * j + 1];
  }
#pragma unroll
  for (int s = 8; s >= 1; s >>= 1)
#pragma unroll
    for (int j = 0; j < s; j++) a[j] += a[j + s];
  float rs = a[0];
  rs += __shfl_xor(rs, 32);
  lrun += rs;

  // P (C-layout) -> B-fragments, in-register (cvt_pk + half-swap)
  int W0[8], W1[8], S0w[8], S1w[8];
#pragma unroll
  for (int j = 0; j < 8; j++) {
    W0[j] = cvtpk(pe0[2 * j], pe0[2 * j + 1]);
    W1[j] = cvtpk(pe1[2 * j], pe1[2 * j + 1]);
  }
#pragma unroll
  for (int j = 0; j < 8; j++) {
    S0w[j] = __shfl_xor(W0[j], 32);
    S1w[j] = __shfl_xor(W1[j], 32);
  }
  bf16x8 pa[4];
  {
    i32x4 w0 = hi ? i32x4{S0w[2], S0w[3], W0[2], W0[3]} : i32x4{W0[0], W0[1], S0w[0], S0w[1]};
    i32x4 w1 = hi ? i32x4{S0w[6], S0w[7], W0[6], W0[7]} : i32x4{W0[4], W0[5], S0w[4], S0w[5]};
    i32x4 w2 = hi ? i32x4{S1w[2], S1w[3], W1[2], W1[3]} : i32x4{W1[0], W1[1], S1w[0], S1w[1]};
    i32x4 w3 = hi ? i32x4{S1w[6], S1w[7], W1[6], W1[7]} : i32x4{W1[4], W1[5], S1w[4], S1w[5]};
    pa[0] = __builtin_bit_cast(bf16x8, w0);
    pa[1] = __builtin_bit_cast(bf16x8, w1);
    pa[2] = __builtin_bit_cast(bf16x8, w2);
    pa[3] = __builtin_bit_cast(bf16x8, w3);
  }

  __builtin_amdgcn_s_setprio(1);
#pragma unroll
  for (int ks = 0; ks < 4; ks++) {
    o[0] = __builtin_amdgcn_mfma_f32_32x32x16_bf16(vfr[ks],      pa[ks], o[0], 0, 0, 0);
    o[1] = __builtin_amdgcn_mfma_f32_32x32x16_bf16(vfr[4 + ks],  pa[ks], o[1], 0, 0, 0);
    o[2] = __builtin_amdgcn_mfma_f32_32x32x16_bf16(vfr[8 + ks],  pa[ks], o[2], 0, 0, 0);
    o[3] = __builtin_amdgcn_mfma_f32_32x32x16_bf16(vfr[12 + ks], pa[ks], o[3], 0, 0, 0);
  }
  __builtin_amdgcn_s_setprio(0);
}

// ---------- Flash attention: 32x32x16 swapped QK/PV, pair-phase K staging (128 keys/barrier) ----------
__global__ __launch_bounds__(256, 2) void k_attn(const unsigned short* __restrict__ Qb,
                                                 const unsigned short* __restrict__ Kf,
                                                 const unsigned short* __restrict__ Vf,
                                                 float* __restrict__ out) {
  __shared__ unsigned short sK[4][10240];   // 4 x 20KB: two K-tile pairs, double-buffered
  const int lane = threadIdx.x & 63, wid = threadIdx.x >> 6;
  const int lanelo = lane & 31, hi = lane >> 5;

  // XCD swizzle: each XCD owns 4 consecutive heads
  const int L = blockIdx.x;
  const int xcd = L & 7, w = L >> 3;
  const int bh = xcd * 4 + (w & 3);
  const int qblk = w >> 2;
  const int b = bh >> 4, h = bh & 15;
  const int q0 = qblk * 128 + wid * 32;

  const unsigned short* Qh = Qb + (size_t)bh * 2048 * 160;
  const unsigned short* Kh = Kf + (size_t)bh * 32 * 10240;
  const unsigned short* Vh = Vf + (size_t)bh * 32 * 8192;

  // Q fragments (B-operand of swapped QK): lane l holds Q[q0+lanelo][ks*16+hi*8 .. +7]
  bf16x8 qf[10];
#pragma unroll
  for (int ks = 0; ks < 10; ks++)
    qf[ks] = *reinterpret_cast<const bf16x8*>(Qh + (size_t)(q0 + lanelo) * 160 + ks * 16 + hi * 8);

  // prologue: stage K pair {0,1} (40 chunks over 4 waves)
#pragma unroll
  for (int i = 0; i < 10; i++) {
    const int chunk = wid * 10 + i;
    stage16(Kh + (size_t)chunk * 512 + lane * 8, &sK[0][0] + chunk * 512, lane);
  }

  f32x16 o[4] = {};
  float mrun = -1e30f, lrun = 0.f;

  asm volatile("s_waitcnt vmcnt(0)" ::: "memory");
  __syncthreads();

  for (int p = 0; p < 16; p++) {
    const int base = (p & 1) * 2;
    // V for sub-iter A FIRST (so later waits don't drain the staging queue)
    bf16x8 vA[16];
    loadV(Vh + (size_t)(2 * p) * 8192, vA, lane);
    // stage next pair (in flight across both sub-iterations)
    if (p < 15) {
      const unsigned short* src = Kh + (size_t)(2 * p + 2) * 10240;
      unsigned short* dst = &sK[base ^ 2][0];
#pragma unroll
      for (int i = 0; i < 10; i++) {
        const int chunk = wid * 10 + i;
        stage16(src + (size_t)chunk * 512 + lane * 8, dst + chunk * 512, lane);
      }
    }
    subiter(&sK[base][0], qf, vA, o, mrun, lrun, lane, hi);
    bf16x8 vB[16];
    loadV(Vh + (size_t)(2 * p + 1) * 8192, vB, lane);
    subiter(&sK[base + 1][0], qf, vB, o, mrun, lrun, lane, hi);

    asm volatile("s_waitcnt vmcnt(0)" ::: "memory");
    __syncthreads();
  }

  // ---- epilogue: O^T -> O via LDS transpose (per-wave region), coalesced store ----
  const float inv = 1.f / lrun;
  float* sO = reinterpret_cast<float*>(&sK[0][0]) + wid * 1152;  // 32 rows x 36 floats
#pragma unroll
  for (int dvt = 0; dvt < 4; dvt++) {
    __syncthreads();
#pragma unroll
    for (int r = 0; r < 16; r++) {
      const int dvl = (r & 3) + 8 * (r >> 2) + 4 * hi;  // crow
      sO[lanelo * 36 + dvl] = o[dvt][r] * inv;
    }
    __syncthreads();
#pragma unroll
    for (int p = 0; p < 4; p++) {
      const int q = p * 8 + (lane >> 3), c = (lane & 7) * 4;
      float4 v = *reinterpret_cast<const float4*>(sO + q * 36 + c);
      *reinterpret_cast<float4*>(out + ((size_t)b * 2048 + q0 + q) * 2048 + h * 128 + dvt * 32 + c) = v;
    }
  }
}

// ---------- launcher ----------
extern "C" void kernel_launch(void* const* d_in, const int* in_sizes, int n_in,
                              void* d_out, int out_size, void* d_ws, size_t ws_size,
                              hipStream_t stream) {
  (void)in_sizes; (void)n_in; (void)out_size;
  const float* x     = (const float*)d_in[0];
  const float* W_DKV = (const float*)d_in[1];
  const float* b_DKV = (const float*)d_in[2];
  const float* W_UK  = (const float*)d_in[3];
  const float* b_UK  = (const float*)d_in[4];
  const float* W_UV  = (const float*)d_in[5];
  const float* b_UV  = (const float*)d_in[6];
  const float* W_DQ  = (const float*)d_in[7];
  const float* b_DQ  = (const float*)d_in[8];
  const float* W_UQ  = (const float*)d_in[9];
  const float* b_UQ  = (const float*)d_in[10];
  const float* W_QR  = (const float*)d_in[11];
  const float* b_QR  = (const float*)d_in[12];
  const float* W_KR  = (const float*)d_in[13];
  const float* b_KR  = (const float*)d_in[14];
  float* out = (float*)d_out;

  char* ws = (char*)d_ws;
  unsigned short* xb     = (unsigned short*)(ws + 0);          // [4096][2048] bf16
  unsigned short* WTcat1 = (unsigned short*)(ws + 16777216);   // [1536][2048] (dkv|dq|kr)
  unsigned short* WTcat2 = (unsigned short*)(ws + 23068672);   // [4096][512]  (uk|uv)
  unsigned short* WTcat3 = (unsigned short*)(ws + 27262976);   // [2560][512]  (uq|qr)
  unsigned short* ckv    = (unsigned short*)(ws + 29884416);   // [4096][512]
  unsigned short* cq     = (unsigned short*)(ws + 34078720);   // [4096][512]
  unsigned short* Qbuf   = (unsigned short*)(ws + 38273024);   // (2,16,2048,160) row-major, *QSCALE
  unsigned short* Kfb    = (unsigned short*)(ws + 59244544);   // frag-linear K (32x32x16 A-op)
  unsigned short* Vfb    = (unsigned short*)(ws + 80216064);   // frag-linear V (32x32x16 A-op)
  float*          qrp    = (float*)(ws + 96993280);            // [4096][512] fp32
  float*          krp    = (float*)(ws + 105381888);           // [4096][512] fp32
  if (ws_size < 113770496) return;

  k_cvt_x<<<8192, 256, 0, stream>>>(x, xb, 8388608);

  TwArgs ta;
  ta.W[0] = W_DKV; ta.D[0] = WTcat1;
  ta.W[1] = W_DQ;  ta.D[1] = WTcat1 + (size_t)512 * 2048;
  ta.W[2] = W_KR;  ta.D[2] = WTcat1 + (size_t)1024 * 2048;
  ta.W[3] = W_UK;  ta.D[3] = WTcat2;
  ta.W[4] = W_UV;  ta.D[4] = WTcat2 + (size_t)2048 * 512;
  ta.W[5] = W_UQ;  ta.D[5] = WTcat3;
  ta.W[6] = W_QR;  ta.D[6] = WTcat3 + (size_t)2048 * 512;
  k_tw_all<<<6400, dim3(32, 8), 0, stream>>>(ta);

  // stage 1: x @ [W_DKV | W_DQ | W_KR]
  k_gemm1<<<dim3(12, 32), 256, 0, stream>>>(xb, WTcat1, b_DKV, b_DQ, b_KR, ckv, cq, krp);
  // stage 2 (merged): ckv @ [UK|UV] -> K/V frag ; cq @ [UQ|QR] -> Q(scaled)/qrp
  k_gemm2<<<dim3(52, 32), 256, 0, stream>>>(ckv, cq, WTcat2, WTcat3,
                                            b_UK, b_UV, b_UQ, b_QR,
                                            Kfb, Vfb, Qbuf, qrp);

  k_rope<<<8192, 256, 0, stream>>>(qrp, krp, Qbuf, Kfb);
  k_attn<<<512, 256, 0, stream>>>(Qbuf, Kfb, Vfb, out);
}

// Round 6
// 340.410 us; speedup vs baseline: 1.0891x; 1.0891x over previous
//
#include <hip/hip_runtime.h>
#include <hip/hip_bf16.h>
#include <cstdint>
#include <cstddef>

// ---------- types / helpers ----------
typedef __attribute__((ext_vector_type(8)))  short bf16x8;
typedef __attribute__((ext_vector_type(4)))  float f32x4;
typedef __attribute__((ext_vector_type(16))) float f32x16;
typedef __attribute__((ext_vector_type(4)))  int   i32x4;

#define DEVINL __device__ __forceinline__

#define QSCALE (0.07905694150420949f * 1.4426950408889634f)  // 1/sqrt(160) * log2(e)

DEVINL unsigned short f2bf(float f) {
  unsigned int u = __float_as_uint(f);
  u += 0x7fff + ((u >> 16) & 1);   // round-to-nearest-even
  return (unsigned short)(u >> 16);
}

DEVINL int cvtpk(float lo, float hi) {   // word = (bf16(lo), bf16(hi))
  int r;
  asm("v_cvt_pk_bf16_f32 %0, %1, %2" : "=v"(r) : "v"(lo), "v"(hi));
  return r;
}

DEVINL void stage16(const unsigned short* __restrict__ g, unsigned short* lds_u) {
  __builtin_amdgcn_global_load_lds((const __attribute__((address_space(1))) void*)g,
                                   (__attribute__((address_space(3))) void*)lds_u, 16, 0, 0);
}

// ---------- prep: x->bf16 (bid<8192) + all 7 weight transposes (bid>=8192) ----------
struct TwArgs { const float* W[7]; unsigned short* D[7]; };
__global__ void k_prep(const float* __restrict__ x, unsigned short* __restrict__ xb, TwArgs a) {
  __shared__ float t[32][33];
  const int bid = blockIdx.x, tid = threadIdx.x;
  if (bid < 8192) {
    const int i = (bid * 256 + tid) * 4;
    float4 v = *reinterpret_cast<const float4*>(x + i);
    ushort4 r;
    r.x = f2bf(v.x); r.y = f2bf(v.y); r.z = f2bf(v.z); r.w = f2bf(v.w);
    *reinterpret_cast<ushort4*>(xb + i) = r;
    return;
  }
  const int tb = bid - 8192;
  int w, K, N, bx, by;
  if (tb < 3072)      { w = tb >> 10; int r = tb & 1023; K = 2048; N = 512;  bx = r & 15; by = r >> 4; }
  else if (tb < 6144) { int r = tb - 3072; w = 3 + (r >> 10); r &= 1023; K = 512; N = 2048; bx = r & 63; by = r >> 6; }
  else                 { int r = tb - 6144; w = 6; K = 512; N = 512; bx = r & 15; by = r >> 4; }
  const float* W = a.W[w];
  unsigned short* D = a.D[w];
  const int n0 = bx * 32, k0 = by * 32;
  const int tx = tid & 31, ty = tid >> 5;
#pragma unroll
  for (int j = 0; j < 4; j++)
    t[ty + j * 8][tx] = W[(size_t)(k0 + ty + j * 8) * N + n0 + tx];
  __syncthreads();
#pragma unroll
  for (int j = 0; j < 4; j++)
    D[(size_t)(n0 + ty + j * 8) * K + k0 + tx] = f2bf(t[tx][ty + j * 8]);
}

// ---------- fragment-linear K/V offsets (32x32x16 MFMA A-operand layout) ----------
DEVINL size_t koff(int bh, int t, int d) {
  const int it = t >> 6, t6 = t & 63;
  const int kvt = t6 >> 5, lanelo = t6 & 31;
  const int ks = d >> 4, hi = (d >> 3) & 1, e = d & 7;
  return ((size_t)bh * 32 + it) * 10240 + (size_t)(kvt * 10 + ks) * 512 + (hi * 32 + lanelo) * 8 + e;
}
DEVINL size_t voff(int bh, int t, int dv) {
  const int it = t >> 6, t6 = t & 63;
  const int ks = t6 >> 4, hi = (t6 >> 3) & 1, e = t6 & 7;
  const int dvt = dv >> 5, lanelo = dv & 31;
  return ((size_t)bh * 32 + it) * 8192 + (size_t)(dvt * 4 + ks) * 512 + (hi * 32 + lanelo) * 8 + e;
}

// ---------- GEMM stage 1: x[4096][2048] @ WTcat1 -> [ckv | cq | krp], BM=128 BN=64, grid (24,32) ----------
__global__ __launch_bounds__(256) void k_gemm1(const unsigned short* __restrict__ A,
                                               const unsigned short* __restrict__ BT,
                                               const float* __restrict__ bias0,
                                               const float* __restrict__ bias1,
                                               const float* __restrict__ bias2,
                                               unsigned short* __restrict__ o0,
                                               unsigned short* __restrict__ o1,
                                               float* __restrict__ o2) {
  __shared__ unsigned short sA[128 * 64];  // 16KB
  __shared__ unsigned short sB[64 * 64];   // 8KB
  const int K = 2048;
  const int tid = threadIdx.x;
  const int lane = tid & 63, wid = tid >> 6;
  const int row0 = blockIdx.y * 128, col0 = blockIdx.x * 64;
  const int lc = lane & 15, lg = lane >> 4;
  const int srow = lane >> 3, scol = (lane & 7) * 8;

  f32x4 acc[2][4];
#pragma unroll
  for (int m = 0; m < 2; m++)
#pragma unroll
    for (int n = 0; n < 4; n++) acc[m][n] = f32x4{0.f, 0.f, 0.f, 0.f};

  for (int k0 = 0; k0 < K; k0 += 64) {
#pragma unroll
    for (int i = 0; i < 6; i++) {
      const int chunk = wid * 6 + i;       // 0..23 (16 A + 8 B)
      if (chunk < 16) {
        stage16(A + (size_t)(row0 + chunk * 8 + srow) * K + k0 + scol, sA + chunk * 512);
      } else {
        const int c = chunk - 16;
        stage16(BT + (size_t)(col0 + c * 8 + srow) * K + k0 + scol, sB + c * 512);
      }
    }
    asm volatile("s_waitcnt vmcnt(0)" ::: "memory");
    __syncthreads();
#pragma unroll
    for (int ks = 0; ks < 2; ks++) {
      bf16x8 af[2], bfr[4];
#pragma unroll
      for (int m = 0; m < 2; m++)
        af[m] = *reinterpret_cast<const bf16x8*>(sA + (wid * 32 + m * 16 + lc) * 64 + ks * 32 + lg * 8);
#pragma unroll
      for (int n = 0; n < 4; n++)
        bfr[n] = *reinterpret_cast<const bf16x8*>(sB + (n * 16 + lc) * 64 + ks * 32 + lg * 8);
#pragma unroll
      for (int m = 0; m < 2; m++)
#pragma unroll
        for (int n = 0; n < 4; n++)
          acc[m][n] = __builtin_amdgcn_mfma_f32_16x16x32_bf16(af[m], bfr[n], acc[m][n], 0, 0, 0);
    }
    __syncthreads();
  }

  const int seg = col0 >> 9;               // uniform per block: 0=ckv 1=cq 2=krp
  const int cofs = col0 - seg * 512;
  const float* bp = (seg == 0) ? bias0 : (seg == 1) ? bias1 : bias2;
  const int lr = lg * 4;
#pragma unroll
  for (int m = 0; m < 2; m++)
#pragma unroll
    for (int n = 0; n < 4; n++) {
      const int c = cofs + n * 16 + lc;
      const float bv = bp[c];
#pragma unroll
      for (int r = 0; r < 4; r++) {
        const int row = row0 + wid * 32 + m * 16 + lr + r;
        const float v = acc[m][n][r] + bv;
        if (seg == 0)      o0[(size_t)row * 512 + c] = f2bf(v);
        else if (seg == 1) o1[(size_t)row * 512 + c] = f2bf(v);
        else               o2[(size_t)row * 512 + c] = v;
      }
    }
}

// ---------- GEMM stage 2 (merged, 128x128): bx<16:K 16..31:V 32..47:Q 48..51:qrp ----------
__global__ __launch_bounds__(256) void k_gemm2(const unsigned short* __restrict__ ckv,
                                               const unsigned short* __restrict__ cq,
                                               const unsigned short* __restrict__ WT2,
                                               const unsigned short* __restrict__ WT3,
                                               const float* __restrict__ bUK,
                                               const float* __restrict__ bUV,
                                               const float* __restrict__ bUQ,
                                               const float* __restrict__ bQR,
                                               unsigned short* __restrict__ Kfb,
                                               unsigned short* __restrict__ Vfb,
                                               unsigned short* __restrict__ Qbuf,
                                               float* __restrict__ qrp) {
  __shared__ unsigned short sA[128 * 64];
  __shared__ unsigned short sB[128 * 64];
  const int K = 512;
  const int bx = blockIdx.x;
  const bool m11 = bx < 32;
  const unsigned short* A  = m11 ? ckv : cq;
  const unsigned short* BT = m11 ? WT2 : WT3;
  const int tid = threadIdx.x;
  const int lane = tid & 63, wid = tid >> 6;
  const int wr = wid >> 1, wc = wid & 1;
  const int row0 = blockIdx.y * 128;
  const int col0 = (m11 ? bx : (bx - 32)) * 128;
  const int lc = lane & 15, lg = lane >> 4;
  const int srow = lane >> 3, scol = (lane & 7) * 8;

  f32x4 acc[4][4];
#pragma unroll
  for (int m = 0; m < 4; m++)
#pragma unroll
    for (int n = 0; n < 4; n++) acc[m][n] = f32x4{0.f, 0.f, 0.f, 0.f};

  for (int k0 = 0; k0 < K; k0 += 64) {
#pragma unroll
    for (int i = 0; i < 4; i++) {
      const int chunk = wid * 4 + i;
      const int r = chunk * 8 + srow;
      stage16(A + (size_t)(row0 + r) * K + k0 + scol, sA + chunk * 512);
      stage16(BT + (size_t)(col0 + r) * K + k0 + scol, sB + chunk * 512);
    }
    asm volatile("s_waitcnt vmcnt(0)" ::: "memory");
    __syncthreads();
#pragma unroll
    for (int ks = 0; ks < 2; ks++) {
      bf16x8 af[4], bfr[4];
#pragma unroll
      for (int m = 0; m < 4; m++)
        af[m] = *reinterpret_cast<const bf16x8*>(sA + (wr * 64 + m * 16 + lc) * 64 + ks * 32 + lg * 8);
#pragma unroll
      for (int n = 0; n < 4; n++)
        bfr[n] = *reinterpret_cast<const bf16x8*>(sB + (wc * 64 + n * 16 + lc) * 64 + ks * 32 + lg * 8);
#pragma unroll
      for (int m = 0; m < 4; m++)
#pragma unroll
        for (int n = 0; n < 4; n++)
          acc[m][n] = __builtin_amdgcn_mfma_f32_16x16x32_bf16(af[m], bfr[n], acc[m][n], 0, 0, 0);
    }
    __syncthreads();
  }

  const int lr = lg * 4;
  const int b = blockIdx.y >> 4;
  const int t0 = (blockIdx.y & 15) * 128;  // t base within sequence

  if (bx < 16) {                       // K fragments, h = bx
    const int bh = b * 16 + bx;
#pragma unroll
    for (int m = 0; m < 4; m++)
#pragma unroll
      for (int n = 0; n < 4; n++) {
        const int d = wc * 64 + n * 16 + lc;
        const float bv = bUK[bx * 128 + d];
        const int t = t0 + wr * 64 + m * 16 + lr;
        const size_t ko = koff(bh, t, d);     // koff(t+r) = koff(t) + 8r  (t 4-aligned)
#pragma unroll
        for (int r = 0; r < 4; r++)
          Kfb[ko + 8 * r] = f2bf(acc[m][n][r] + bv);
      }
  } else if (bx < 32) {                // V fragments, h = bx-16; voff(t+r)=voff(t)+r
    const int h = bx - 16, bh = b * 16 + h;
#pragma unroll
    for (int m = 0; m < 4; m++)
#pragma unroll
      for (int n = 0; n < 4; n++) {
        const int dv = wc * 64 + n * 16 + lc;
        const float bv = bUV[h * 128 + dv];
        const int t = t0 + wr * 64 + m * 16 + lr;
        const size_t vo = voff(bh, t, dv);
        ushort4 pk;
        pk.x = f2bf(acc[m][n][0] + bv);
        pk.y = f2bf(acc[m][n][1] + bv);
        pk.z = f2bf(acc[m][n][2] + bv);
        pk.w = f2bf(acc[m][n][3] + bv);
        *reinterpret_cast<ushort4*>(Vfb + vo) = pk;
      }
  } else if (bx < 48) {                // Q row-major *QSCALE, h = bx-32
    const int h = bx - 32;
#pragma unroll
    for (int m = 0; m < 4; m++)
#pragma unroll
      for (int n = 0; n < 4; n++) {
        const int d = wc * 64 + n * 16 + lc;
        const float bv = bUQ[h * 128 + d];
        const int t = t0 + wr * 64 + m * 16 + lr;
        size_t qo = ((size_t)(b * 16 + h) * 2048 + t) * 160 + d;
#pragma unroll
        for (int r = 0; r < 4; r++) {
          Qbuf[qo] = f2bf((acc[m][n][r] + bv) * QSCALE);
          qo += 160;
        }
      }
  } else {                             // qrp fp32 [row][512]
    const int c0 = (bx - 48) * 128;
#pragma unroll
    for (int m = 0; m < 4; m++)
#pragma unroll
      for (int n = 0; n < 4; n++) {
        const int c = c0 + wc * 64 + n * 16 + lc;
        const float bv = bQR[c];
#pragma unroll
        for (int r = 0; r < 4; r++) {
          const int row = blockIdx.y * 128 + wr * 64 + m * 16 + lr + r;
          qrp[(size_t)row * 512 + c] = acc[m][n][r] + bv;
        }
      }
  }
}

// ---------- RoPE: pre[row][512] fp32 -> Q(row-major, QSCALE) / K(frag layout) ----------
__global__ void k_rope(const float* __restrict__ qpre, const float* __restrict__ kpre,
                       unsigned short* __restrict__ Qb, unsigned short* __restrict__ Kf) {
  const int idx = blockIdx.x * blockDim.x + threadIdx.x;
  const int which = idx >> 20;
  const int e = idx & 1048575;
  const int i = e & 15, h = (e >> 4) & 15, row = e >> 8;
  const int t = row & 2047, b = row >> 11;
  const float* pre = which ? kpre : qpre;
  const float x1 = pre[(size_t)row * 512 + h * 32 + 2 * i];
  const float x2 = pre[(size_t)row * 512 + h * 32 + 2 * i + 1];
  const float f = exp2f(-(float)i * (13.287712379549449f / 16.f));  // 10000^(-i/16)
  const float th = (float)t * f;
  float sv, cv;
  sincosf(th, &sv, &cv);
  const float o1 = x1 * cv - x2 * sv, o2 = x1 * sv + x2 * cv;
  if (which == 0) {
    const size_t base = ((size_t)(b * 16 + h) * 2048 + t) * 160 + 128;
    Qb[base + i]      = f2bf(o1 * QSCALE);
    Qb[base + 16 + i] = f2bf(o2 * QSCALE);
  } else {
    Kf[koff(b * 16 + h, t, 128 + i)] = f2bf(o1);
    Kf[koff(b * 16 + h, t, 144 + i)] = f2bf(o2);
  }
}

// ---------- Flash attention (round-4 structure; V loads issued before K staging; tree reductions) ----------
__global__ __launch_bounds__(256, 2) void k_attn(const unsigned short* __restrict__ Qb,
                                                 const unsigned short* __restrict__ Kf,
                                                 const unsigned short* __restrict__ Vf,
                                                 float* __restrict__ out) {
  __shared__ unsigned short sK[2][10240];   // 20KB x2 frag-linear K
  const int lane = threadIdx.x & 63, wid = threadIdx.x >> 6;
  const int lanelo = lane & 31, hi = lane >> 5;

  const int L = blockIdx.x;
  const int xcd = L & 7, w = L >> 3;
  const int bh = xcd * 4 + (w & 3);
  const int qblk = w >> 2;
  const int b = bh >> 4, h = bh & 15;
  const int q0 = qblk * 128 + wid * 32;

  const unsigned short* Qh = Qb + (size_t)bh * 2048 * 160;
  const unsigned short* Kh = Kf + (size_t)bh * 32 * 10240;
  const unsigned short* Vh = Vf + (size_t)bh * 32 * 8192;

  bf16x8 qf[10];
#pragma unroll
  for (int ks = 0; ks < 10; ks++)
    qf[ks] = *reinterpret_cast<const bf16x8*>(Qh + (size_t)(q0 + lanelo) * 160 + ks * 16 + hi * 8);

#pragma unroll
  for (int i = 0; i < 5; i++) {
    const int chunk = wid * 5 + i;
    stage16(Kh + (size_t)chunk * 512 + lane * 8, &sK[0][0] + chunk * 512);
  }

  f32x16 o[4] = {};
  float mrun = -1e30f, lrun = 0.f;

  asm volatile("s_waitcnt vmcnt(0)" ::: "memory");
  __syncthreads();

  int buf = 0;
  for (int it = 0; it < 32; it++) {
    // V first: PV's wait for V then leaves K-staging in flight (vmcnt FIFO)
    bf16x8 vf[16];
    {
      const unsigned short* Vt = Vh + (size_t)it * 8192;
#pragma unroll
      for (int f = 0; f < 16; f++)
        vf[f] = *reinterpret_cast<const bf16x8*>(Vt + (size_t)f * 512 + lane * 8);
    }
    if (it < 31) {
      const unsigned short* src = Kh + (size_t)(it + 1) * 10240;
      unsigned short* dst = &sK[buf ^ 1][0];
#pragma unroll
      for (int i = 0; i < 5; i++) {
        const int chunk = wid * 5 + i;
        stage16(src + (size_t)chunk * 512 + lane * 8, dst + chunk * 512);
      }
    }
    // QK^T (swapped): A=K frag from LDS, B=Q frag
    f32x16 s0 = {}, s1 = {};
    const unsigned short* sKb = &sK[buf][0];
#pragma unroll
    for (int ks = 0; ks < 10; ks++) {
      bf16x8 kf0 = *reinterpret_cast<const bf16x8*>(sKb + (size_t)ks * 512 + lane * 8);
      s0 = __builtin_amdgcn_mfma_f32_32x32x16_bf16(kf0, qf[ks], s0, 0, 0, 0);
      bf16x8 kf1 = *reinterpret_cast<const bf16x8*>(sKb + (size_t)(10 + ks) * 512 + lane * 8);
      s1 = __builtin_amdgcn_mfma_f32_32x32x16_bf16(kf1, qf[ks], s1, 0, 0, 0);
    }

    // ---- online softmax (exp2 domain), tree reductions ----
    float tm[16];
#pragma unroll
    for (int j = 0; j < 16; j++) tm[j] = fmaxf(s0[j], s1[j]);
#pragma unroll
    for (int s = 8; s >= 1; s >>= 1)
#pragma unroll
      for (int j = 0; j < s; j++) tm[j] = fmaxf(tm[j], tm[j + s]);
    float mx = fmaxf(tm[0], __shfl_xor(tm[0], 32));

    if (__any(mx > mrun + 8.f)) {          // defer-max
      const float mn = fmaxf(mrun, mx);
      const float corr = exp2f(mrun - mn);
      lrun *= corr;
#pragma unroll
      for (int d = 0; d < 4; d++)
#pragma unroll
        for (int r = 0; r < 16; r++) o[d][r] *= corr;
      mrun = mn;
    }

    float pe0[16], pe1[16];
#pragma unroll
    for (int r = 0; r < 16; r++) pe0[r] = exp2f(s0[r] - mrun);
#pragma unroll
    for (int r = 0; r < 16; r++) pe1[r] = exp2f(s1[r] - mrun);
    float ta[16];
#pragma unroll
    for (int j = 0; j < 8; j++) {
      ta[j]     = pe0[2 * j] + pe0[2 * j + 1];
      ta[8 + j] = pe1[2 * j] + pe1[2 * j + 1];
    }
#pragma unroll
    for (int s = 8; s >= 1; s >>= 1)
#pragma unroll
      for (int j = 0; j < s; j++) ta[j] += ta[j + s];
    lrun += ta[0] + __shfl_xor(ta[0], 32);

    // ---- P (C-layout) -> B-fragments in-register ----
    int W0[8], W1[8], S0w[8], S1w[8];
#pragma unroll
    for (int j = 0; j < 8; j++) {
      W0[j] = cvtpk(pe0[2 * j], pe0[2 * j + 1]);
      W1[j] = cvtpk(pe1[2 * j], pe1[2 * j + 1]);
    }
#pragma unroll
    for (int j = 0; j < 8; j++) {
      S0w[j] = __shfl_xor(W0[j], 32);
      S1w[j] = __shfl_xor(W1[j], 32);
    }
    bf16x8 pa[4];
    {
      i32x4 w0 = hi ? i32x4{S0w[2], S0w[3], W0[2], W0[3]} : i32x4{W0[0], W0[1], S0w[0], S0w[1]};
      i32x4 w1 = hi ? i32x4{S0w[6], S0w[7], W0[6], W0[7]} : i32x4{W0[4], W0[5], S0w[4], S0w[5]};
      i32x4 w2 = hi ? i32x4{S1w[2], S1w[3], W1[2], W1[3]} : i32x4{W1[0], W1[1], S1w[0], S1w[1]};
      i32x4 w3 = hi ? i32x4{S1w[6], S1w[7], W1[6], W1[7]} : i32x4{W1[4], W1[5], S1w[4], S1w[5]};
      pa[0] = __builtin_bit_cast(bf16x8, w0);
      pa[1] = __builtin_bit_cast(bf16x8, w1);
      pa[2] = __builtin_bit_cast(bf16x8, w2);
      pa[3] = __builtin_bit_cast(bf16x8, w3);
    }

    // ---- PV (swapped): O^T += V^T . P^T ----
#pragma unroll
    for (int ks = 0; ks < 4; ks++) {
      o[0] = __builtin_amdgcn_mfma_f32_32x32x16_bf16(vf[ks],      pa[ks], o[0], 0, 0, 0);
      o[1] = __builtin_amdgcn_mfma_f32_32x32x16_bf16(vf[4 + ks],  pa[ks], o[1], 0, 0, 0);
      o[2] = __builtin_amdgcn_mfma_f32_32x32x16_bf16(vf[8 + ks],  pa[ks], o[2], 0, 0, 0);
      o[3] = __builtin_amdgcn_mfma_f32_32x32x16_bf16(vf[12 + ks], pa[ks], o[3], 0, 0, 0);
    }

    asm volatile("s_waitcnt vmcnt(0)" ::: "memory");
    __syncthreads();
    buf ^= 1;
  }

  // ---- epilogue: O^T -> O via LDS transpose, coalesced store ----
  const float inv = 1.f / lrun;
  float* sO = reinterpret_cast<float*>(&sK[0][0]) + wid * 1152;  // 32 rows x 36 floats
#pragma unroll
  for (int dvt = 0; dvt < 4; dvt++) {
    __syncthreads();
#pragma unroll
    for (int r = 0; r < 16; r++) {
      const int dvl = (r & 3) + 8 * (r >> 2) + 4 * hi;  // crow
      sO[lanelo * 36 + dvl] = o[dvt][r] * inv;
    }
    __syncthreads();
#pragma unroll
    for (int p = 0; p < 4; p++) {
      const int q = p * 8 + (lane >> 3), c = (lane & 7) * 4;
      float4 v = *reinterpret_cast<const float4*>(sO + q * 36 + c);
      *reinterpret_cast<float4*>(out + ((size_t)b * 2048 + q0 + q) * 2048 + h * 128 + dvt * 32 + c) = v;
    }
  }
}

// ---------- launcher ----------
extern "C" void kernel_launch(void* const* d_in, const int* in_sizes, int n_in,
                              void* d_out, int out_size, void* d_ws, size_t ws_size,
                              hipStream_t stream) {
  (void)in_sizes; (void)n_in; (void)out_size;
  const float* x     = (const float*)d_in[0];
  const float* W_DKV = (const float*)d_in[1];
  const float* b_DKV = (const float*)d_in[2];
  const float* W_UK  = (const float*)d_in[3];
  const float* b_UK  = (const float*)d_in[4];
  const float* W_UV  = (const float*)d_in[5];
  const float* b_UV  = (const float*)d_in[6];
  const float* W_DQ  = (const float*)d_in[7];
  const float* b_DQ  = (const float*)d_in[8];
  const float* W_UQ  = (const float*)d_in[9];
  const float* b_UQ  = (const float*)d_in[10];
  const float* W_QR  = (const float*)d_in[11];
  const float* b_QR  = (const float*)d_in[12];
  const float* W_KR  = (const float*)d_in[13];
  const float* b_KR  = (const float*)d_in[14];
  float* out = (float*)d_out;

  char* ws = (char*)d_ws;
  unsigned short* xb     = (unsigned short*)(ws + 0);          // [4096][2048] bf16
  unsigned short* WTcat1 = (unsigned short*)(ws + 16777216);   // [1536][2048] (dkv|dq|kr)
  unsigned short* WTcat2 = (unsigned short*)(ws + 23068672);   // [4096][512]  (uk|uv)
  unsigned short* WTcat3 = (unsigned short*)(ws + 27262976);   // [2560][512]  (uq|qr)
  unsigned short* ckv    = (unsigned short*)(ws + 29884416);   // [4096][512]
  unsigned short* cq     = (unsigned short*)(ws + 34078720);   // [4096][512]
  unsigned short* Qbuf   = (unsigned short*)(ws + 38273024);   // (2,16,2048,160) row-major, *QSCALE
  unsigned short* Kfb    = (unsigned short*)(ws + 59244544);   // frag-linear K
  unsigned short* Vfb    = (unsigned short*)(ws + 80216064);   // frag-linear V
  float*          qrp    = (float*)(ws + 96993280);            // [4096][512] fp32
  float*          krp    = (float*)(ws + 105381888);           // [4096][512] fp32
  if (ws_size < 113770496) return;

  TwArgs ta;
  ta.W[0] = W_DKV; ta.D[0] = WTcat1;
  ta.W[1] = W_DQ;  ta.D[1] = WTcat1 + (size_t)512 * 2048;
  ta.W[2] = W_KR;  ta.D[2] = WTcat1 + (size_t)1024 * 2048;
  ta.W[3] = W_UK;  ta.D[3] = WTcat2;
  ta.W[4] = W_UV;  ta.D[4] = WTcat2 + (size_t)2048 * 512;
  ta.W[5] = W_UQ;  ta.D[5] = WTcat3;
  ta.W[6] = W_QR;  ta.D[6] = WTcat3 + (size_t)2048 * 512;
  k_prep<<<14592, 256, 0, stream>>>(x, xb, ta);

  k_gemm1<<<dim3(24, 32), 256, 0, stream>>>(xb, WTcat1, b_DKV, b_DQ, b_KR, ckv, cq, krp);
  k_gemm2<<<dim3(52, 32), 256, 0, stream>>>(ckv, cq, WTcat2, WTcat3,
                                            b_UK, b_UV, b_UQ, b_QR,
                                            Kfb, Vfb, Qbuf, qrp);

  k_rope<<<8192, 256, 0, stream>>>(qrp, krp, Qbuf, Kfb);
  k_attn<<<512, 256, 0, stream>>>(Qbuf, Kfb, Vfb, out);
}